// Round 4
// baseline (7283.347 us; speedup 1.0000x reference)
//
#include <hip/hip_runtime.h>
#include <hip/hip_bf16.h>
#include <cstdint>

// ---------------------------------------------------------------------------
// BiLSTM: x[2048,1024] -> bidirectional LSTM (H=1024) -> FC to 1000 classes.
//   1. convert_all: fp32 -> f16 copies of x, W_ih_f, W_ih_b, fc_W
//   2. gemm_f16<0>: x_proj_d = x_d @ W_ih_d^T + b_ih + b_hh   (f16 MFMA)
//   3. lstm_rec R4: 128 blocks x 512 thr (8 waves). Wave w owns h-outputs
//      {2w,2w+1}: lane = [jloc(1)|gate(2)|kseg(3)]. Entire post-dot path
//      (k-reduce, gate gather, cell, publish) is IN-WAVE -> one barrier/step.
//      Poll: 1 u64/thread ([h2|seq] embedded), double-pumped (2 in flight).
//      xp(t+1) prefetched after the poll (vmcnt is FIFO: anything issued
//      before the poll loads lands on the critical path - R3 mistake).
//      LDS h double-buffered; per-kseg stride 68 dwords (bank-safe).
//   4. gemm_f16<1>: out = h_hist @ fc_W^T + fc_b
// ---------------------------------------------------------------------------

typedef __fp16 h2 __attribute__((ext_vector_type(2)));
typedef __fp16 h8 __attribute__((ext_vector_type(8)));
typedef float f4 __attribute__((ext_vector_type(4)));
typedef unsigned long long u64;

#define T_LEN 2048

static __device__ __forceinline__ unsigned int packh2(float a, float b) {
  h2 r = __builtin_amdgcn_cvt_pkrtz(a, b);
  return __builtin_bit_cast(unsigned int, r);
}
static __device__ __forceinline__ float fdot2u(unsigned int a, unsigned int b, float c) {
  return __builtin_amdgcn_fdot2(__builtin_bit_cast(h2, a), __builtin_bit_cast(h2, b), c, false);
}
static __device__ __forceinline__ float sigmoidf_(float x) {
  return 1.f / (1.f + __expf(-x));
}
static __device__ __forceinline__ float tanhf_(float x) {
  float e = __expf(-2.f * fabsf(x));
  float r = (1.f - e) / (1.f + e);
  return copysignf(r, x);
}

// ---------------------------------------------------------------------------
__global__ void convert_all(const float* __restrict__ x, const float* __restrict__ wf,
                            const float* __restrict__ wb, const float* __restrict__ fcw,
                            _Float16* __restrict__ xf, _Float16* __restrict__ wff,
                            _Float16* __restrict__ wbf, _Float16* __restrict__ fcwf) {
  const size_t SX = 2097152, SW = 4194304, SFC = 2097152;
  size_t i = (size_t)blockIdx.x * 256 + threadIdx.x;
  if (i < SX) {
    xf[i] = (_Float16)x[i];
  } else if (i < SX + SW) {
    size_t j = i - SX; wff[j] = (_Float16)wf[j];
  } else if (i < SX + 2 * SW) {
    size_t j = i - SX - SW; wbf[j] = (_Float16)wb[j];
  } else if (i < SX + 2 * SW + SFC) {
    size_t j = i - SX - 2 * SW;
    int row = (int)(j >> 11), col = (int)(j & 2047);
    fcwf[j] = (row < 1000) ? (_Float16)fcw[(size_t)row * 2048 + col] : (_Float16)0.f;
  }
}

// zero the h-communication buffers: gen 0 == valid zeros for t=0
__global__ void init_state(u64* __restrict__ hc) {
  int t = threadIdx.x;
  for (int i = t; i < 2048; i += 256) hc[i] = 0ull;
}

// ---------------------------------------------------------------------------
// f16 GEMM, 128x128 tile, BK=64 (unchanged — verified R2/R3)
// ---------------------------------------------------------------------------
#define LSTR 80

template <int MODE>
__global__ __launch_bounds__(256, 2) void gemm_f16(
    const _Float16* __restrict__ A, const _Float16* __restrict__ B,
    const float* __restrict__ bias1, const float* __restrict__ bias2,
    void* __restrict__ Cout, int M, int N, int K, int nout, int rev) {
  __shared__ _Float16 As[128 * LSTR];
  __shared__ _Float16 Bs[128 * LSTR];

  const int tid = threadIdx.x;
  const int ntn = N >> 7;
  const int tm = blockIdx.x / ntn, tn = blockIdx.x % ntn;
  const int wid = tid >> 6, lane = tid & 63;
  const int wr = wid >> 1, wc = wid & 1;
  const int quad = lane >> 4, l16 = lane & 15;

  const int srow = tid >> 1, seg = tid & 1;
  const int arow = rev ? (M - 1 - (tm * 128 + srow)) : (tm * 128 + srow);
  const int brow = tn * 128 + srow;

  f4 acc[4][4];
#pragma unroll
  for (int i = 0; i < 4; ++i)
#pragma unroll
    for (int j = 0; j < 4; ++j) acc[i][j] = (f4)0.f;

  for (int k0 = 0; k0 < K; k0 += 64) {
    uint4 va[4], vb[4];
    const uint4* gpa = (const uint4*)(A + (size_t)arow * K + k0 + seg * 32);
    const uint4* gpb = (const uint4*)(B + (size_t)brow * K + k0 + seg * 32);
#pragma unroll
    for (int c = 0; c < 4; ++c) va[c] = gpa[c];
#pragma unroll
    for (int c = 0; c < 4; ++c) vb[c] = gpb[c];

    __syncthreads();
    uint4* lpa = (uint4*)&As[srow * LSTR + seg * 32];
    uint4* lpb = (uint4*)&Bs[srow * LSTR + seg * 32];
#pragma unroll
    for (int c = 0; c < 4; ++c) lpa[c] = va[c];
#pragma unroll
    for (int c = 0; c < 4; ++c) lpb[c] = vb[c];
    __syncthreads();

#pragma unroll
    for (int kk = 0; kk < 64; kk += 32) {
      h8 af[4], bf[4];
#pragma unroll
      for (int i = 0; i < 4; ++i) {
        int m = wr * 64 + i * 16 + l16;
        af[i] = *(const h8*)&As[m * LSTR + kk + quad * 8];
        int n = wc * 64 + i * 16 + l16;
        bf[i] = *(const h8*)&Bs[n * LSTR + kk + quad * 8];
      }
#pragma unroll
      for (int i = 0; i < 4; ++i)
#pragma unroll
        for (int j = 0; j < 4; ++j)
          acc[i][j] = __builtin_amdgcn_mfma_f32_16x16x32_f16(af[i], bf[j], acc[i][j], 0, 0, 0);
    }
  }

  const int cm0 = tm * 128 + wr * 64, cn0 = tn * 128 + wc * 64;
#pragma unroll
  for (int i = 0; i < 4; ++i) {
#pragma unroll
    for (int j = 0; j < 4; ++j) {
      int n = cn0 + j * 16 + l16;
#pragma unroll
      for (int r = 0; r < 4; ++r) {
        int m = cm0 + i * 16 + quad * 4 + r;
        float v = acc[i][j][r];
        if (MODE == 0) {
          v += bias1[n] + bias2[n];
          ((_Float16*)Cout)[(size_t)m * N + n] = (_Float16)v;
        } else {
          if (n < nout) ((float*)Cout)[(size_t)m * nout + n] = v + bias1[n];
        }
      }
    }
  }
}

// ---------------------------------------------------------------------------
// Persistent BiLSTM recurrence, R4 in-wave cell design.
// 128 blocks x 512 thr. blk<64 fwd, else bwd. Block owns 16 h (j0..j0+15)
// = 64 W_hh rows of 1024. Wave wv owns jj in {2wv, 2wv+1}.
// lane l: jloc=l>>5, gate=(l>>3)&3, kseg=l&7; W row = gate*1024+j0+jj,
// k-slice = kseg*128..+127 (64 h2 dwords in regs).
// hc: [buf][dir][512] u64; word g = [h2(h[2g],h[2g+1]) | seq].
// Consumer step t polls buf t&1 for seq==t; producer stores seq=t+1 into
// buf (t+1)&1. 2-buffer safety: a block reaching step t+2 implies all
// blocks finished reading gen t+1 (publish data-depends on its polls).
// ---------------------------------------------------------------------------
__global__ __launch_bounds__(512, 1) void lstm_rec(
    const float* __restrict__ Whh_f, const float* __restrict__ Whh_b,
    const _Float16* __restrict__ xp,   // [2][2048][4096]
    u64* __restrict__ hc,              // [2][2][512]
    _Float16* __restrict__ hhist) {    // [2048][2048]
  const int tid = threadIdx.x;
  const int blk = blockIdx.x;
  const int dir = blk >> 6;
  const int ib = blk & 63;
  const int j0 = ib * 16;
  const int wv = tid >> 6;
  const int l = tid & 63;
  const int jloc = l >> 5;
  const int gate = (l >> 3) & 3;
  const int kseg = l & 7;
  const int jj = 2 * wv + jloc;
  const int wrow = gate * 1024 + j0 + jj;

  const float* Whh = dir ? Whh_b : Whh_f;
  const _Float16* xpd = xp + (size_t)dir * (2048u * 4096u);

  __shared__ unsigned int lds_h[2][8 * 68];  // [buf][kseg stride 68]

  // one-time: W_hh[wrow][kseg*128 .. +127] -> 64 h2 dwords in regs
  unsigned int w[64];
  {
    const float* wp = Whh + (size_t)wrow * 1024 + kseg * 128;
#pragma unroll
    for (int i = 0; i < 32; ++i) {
      float4 v = ((const float4*)wp)[i];
      w[2 * i] = packh2(v.x, v.y);
      w[2 * i + 1] = packh2(v.z, v.w);
    }
  }

  float c = 0.f;                      // cell state (replicated per half-wave)
  float xpv = (float)xpd[wrow];       // x_proj for t=0

  for (int t = 0; t < T_LEN; ++t) {
    // ---- poll own word (group g = tid), double-pumped ----
    unsigned hbits;
    {
      u64* src = hc + (((size_t)(t & 1) * 2 + dir) * 512 + tid);
      u64 a = __hip_atomic_load(src, __ATOMIC_RELAXED, __HIP_MEMORY_SCOPE_AGENT);
      u64 b = __hip_atomic_load(src, __ATOMIC_RELAXED, __HIP_MEMORY_SCOPE_AGENT);
      int cnt = 0;
      while (true) {
        if ((unsigned)a == (unsigned)t) { hbits = (unsigned)(a >> 32); break; }
        a = __hip_atomic_load(src, __ATOMIC_RELAXED, __HIP_MEMORY_SCOPE_AGENT);
        if ((unsigned)b == (unsigned)t) { hbits = (unsigned)(b >> 32); break; }
        b = __hip_atomic_load(src, __ATOMIC_RELAXED, __HIP_MEMORY_SCOPE_AGENT);
        if (++cnt > (1 << 13)) { hbits = (unsigned)(a >> 32); break; }  // no-hang bailout
      }
      lds_h[t & 1][wv * 68 + l] = hbits;  // word g at seg g>>6 (=wv), off g&63 (=l)
    }
    __syncthreads();  // single barrier per step (LDS double-buffered)

    // prefetch NEXT step's x_proj (issued after poll loads -> off critical path)
    int tn = (t + 1 < T_LEN) ? t + 1 : t;
    float xpn = (float)xpd[(size_t)tn * 4096 + wrow];

    // ---- dot: own row x 128-elem k-slice (16 ds_read_b128, 64 fdot2) ----
    float acc = 0.f;
    const uint4* hp = (const uint4*)&lds_h[t & 1][kseg * 68];
#pragma unroll
    for (int i = 0; i < 16; ++i) {
      uint4 hv = hp[i];
      acc = fdot2u(w[4 * i + 0], hv.x, acc);
      acc = fdot2u(w[4 * i + 1], hv.y, acc);
      acc = fdot2u(w[4 * i + 2], hv.z, acc);
      acc = fdot2u(w[4 * i + 3], hv.w, acc);
    }
    // reduce across kseg (lane bits 0..2)
    acc += __shfl_xor(acc, 1, 64);
    acc += __shfl_xor(acc, 2, 64);
    acc += __shfl_xor(acc, 4, 64);
    float val = acc + xpv;  // gate pre-activation, valid at kseg==0 lanes

    // gather 4 gates in-wave (sources are kseg==0 lanes)
    int base = jloc * 32;
    float gi = __shfl(val, base + 0, 64);
    float gf = __shfl(val, base + 8, 64);
    float gg = __shfl(val, base + 16, 64);
    float go = __shfl(val, base + 24, 64);

    float ii = sigmoidf_(gi);
    float ff = sigmoidf_(gf);
    float g_ = tanhf_(gg);
    float oo = sigmoidf_(go);
    c = ff * c + ii * g_;
    float h = oo * tanhf_(c);  // jj=2wv in lanes 0..31, jj=2wv+1 in 32..63

    float h_odd = __shfl(h, 32, 64);
    if (l == 0) {
      unsigned hh = packh2(h, h_odd);
      u64 word = ((u64)hh << 32) | (unsigned)(t + 1);
      u64* dst = hc + (((size_t)((t + 1) & 1) * 2 + dir) * 512 + (ib * 8 + wv));
      __hip_atomic_store(dst, word, __ATOMIC_RELAXED, __HIP_MEMORY_SCOPE_AGENT);
      // hhist AFTER publish, one packed u32 per wave
      int tout = dir ? (T_LEN - 1 - t) : t;
      *(unsigned*)&hhist[(size_t)tout * 2048 + dir * 1024 + j0 + 2 * wv] = hh;
    }
    xpv = xpn;
  }
}

// ---------------------------------------------------------------------------
extern "C" void kernel_launch(void* const* d_in, const int* in_sizes, int n_in,
                              void* d_out, int out_size, void* d_ws, size_t ws_size,
                              hipStream_t stream) {
  (void)in_sizes; (void)n_in; (void)out_size; (void)ws_size;
  const float* x     = (const float*)d_in[0];
  const float* Wih_f = (const float*)d_in[1];
  const float* Whh_f = (const float*)d_in[2];
  const float* bih_f = (const float*)d_in[3];
  const float* bhh_f = (const float*)d_in[4];
  const float* Wih_b = (const float*)d_in[5];
  const float* Whh_b = (const float*)d_in[6];
  const float* bih_b = (const float*)d_in[7];
  const float* bhh_b = (const float*)d_in[8];
  const float* fcW   = (const float*)d_in[9];
  const float* fcb   = (const float*)d_in[10];

  char* ws = (char*)d_ws;
  _Float16* xf16   = (_Float16*)(ws + 0);
  _Float16* wih16f = (_Float16*)(ws + 4194304);
  _Float16* wih16b = (_Float16*)(ws + 12582912);
  _Float16* fcw16  = (_Float16*)(ws + 20971520);
  _Float16* xp16   = (_Float16*)(ws + 25165824);   // [2][2048][4096]
  _Float16* hhist  = (_Float16*)(ws + 58720256);   // [2048][2048]
  u64*      hc     = (u64*)     (ws + 67108864);   // [2][2][512]

  const size_t SX = 2097152, SW = 4194304, SFC = 2097152;
  const size_t total_cvt = SX + 2 * SW + SFC;

  convert_all<<<dim3((unsigned)((total_cvt + 255) / 256)), 256, 0, stream>>>(
      x, Wih_f, Wih_b, fcW, xf16, wih16f, wih16b, fcw16);
  init_state<<<1, 256, 0, stream>>>(hc);

  gemm_f16<0><<<dim3(512), 256, 0, stream>>>(xf16, wih16f, bih_f, bhh_f,
                                             (void*)xp16, 2048, 4096, 1024, 4096, 0);
  gemm_f16<0><<<dim3(512), 256, 0, stream>>>(xf16, wih16b, bih_b, bhh_b,
                                             (void*)(xp16 + (size_t)2048 * 4096),
                                             2048, 4096, 1024, 4096, 1);

  lstm_rec<<<dim3(128), 512, 0, stream>>>(Whh_f, Whh_b, xp16, hc, hhist);

  gemm_f16<1><<<dim3(128), 256, 0, stream>>>(hhist, fcw16, fcb, nullptr,
                                             d_out, 2048, 1024, 2048, 1000, 0);
}

// Round 5
// 3736.168 us; speedup vs baseline: 1.9494x; 1.9494x over previous
//
#include <hip/hip_runtime.h>
#include <hip/hip_bf16.h>
#include <cstdint>

// ---------------------------------------------------------------------------
// BiLSTM: x[2048,1024] -> bidirectional LSTM (H=1024) -> FC to 1000 classes.
//   1. convert_all: fp32 -> f16 copies of x, W_ih_f, W_ih_b, fc_W
//   2. gemm_f16<0>: x_proj_d = x_d @ W_ih_d^T + b_ih + b_hh   (f16 MFMA)
//   3. lstm_rec R5: 128 blocks x 256 thr (4 waves). Wave wv owns jj
//      {4wv..4wv+3} with ALL 4 gates: lane=[gate(2)|kq(4)], thread = 4 rows
//      (same gate, 4 consecutive jj) x 64-elem k-slice -> each h uint4 LDS
//      read feeds 4 rows (R3's efficiency: 2048 b128/blk/step, vs R4's 8192
//      which serialized ~640ns/step on the LDS pipe - the R4 regression).
//      Single barrier/step (LDS h double-buffered); post-dot path in-wave:
//      butterfly reduce over kq, 16B LDS transpose (same-wave, no barrier),
//      replicated cell, lane0 publishes 2 contiguous seq-embedded u64s.
//      xp(t+1) prefetched right after poll (vmcnt-FIFO safe).
//   4. gemm_f16<1>: out = h_hist @ fc_W^T + fc_b
// ---------------------------------------------------------------------------

typedef __fp16 h2 __attribute__((ext_vector_type(2)));
typedef __fp16 h8 __attribute__((ext_vector_type(8)));
typedef float f4 __attribute__((ext_vector_type(4)));
typedef unsigned long long u64;

#define T_LEN 2048

static __device__ __forceinline__ unsigned int packh2(float a, float b) {
  h2 r = __builtin_amdgcn_cvt_pkrtz(a, b);
  return __builtin_bit_cast(unsigned int, r);
}
static __device__ __forceinline__ float fdot2u(unsigned int a, unsigned int b, float c) {
  return __builtin_amdgcn_fdot2(__builtin_bit_cast(h2, a), __builtin_bit_cast(h2, b), c, false);
}
static __device__ __forceinline__ float sigmoidf_(float x) {
  return 1.f / (1.f + __expf(-x));
}
static __device__ __forceinline__ float tanhf_(float x) {
  float e = __expf(-2.f * fabsf(x));
  float r = (1.f - e) / (1.f + e);
  return copysignf(r, x);
}

// ---------------------------------------------------------------------------
__global__ void convert_all(const float* __restrict__ x, const float* __restrict__ wf,
                            const float* __restrict__ wb, const float* __restrict__ fcw,
                            _Float16* __restrict__ xf, _Float16* __restrict__ wff,
                            _Float16* __restrict__ wbf, _Float16* __restrict__ fcwf) {
  const size_t SX = 2097152, SW = 4194304, SFC = 2097152;
  size_t i = (size_t)blockIdx.x * 256 + threadIdx.x;
  if (i < SX) {
    xf[i] = (_Float16)x[i];
  } else if (i < SX + SW) {
    size_t j = i - SX; wff[j] = (_Float16)wf[j];
  } else if (i < SX + 2 * SW) {
    size_t j = i - SX - SW; wbf[j] = (_Float16)wb[j];
  } else if (i < SX + 2 * SW + SFC) {
    size_t j = i - SX - 2 * SW;
    int row = (int)(j >> 11), col = (int)(j & 2047);
    fcwf[j] = (row < 1000) ? (_Float16)fcw[(size_t)row * 2048 + col] : (_Float16)0.f;
  }
}

// zero the h-communication buffers: gen 0 == valid zeros for t=0
__global__ void init_state(u64* __restrict__ hc) {
  int t = threadIdx.x;
  for (int i = t; i < 2048; i += 256) hc[i] = 0ull;
}

// ---------------------------------------------------------------------------
// f16 GEMM, 128x128 tile, BK=64 (unchanged — verified R2/R3/R4)
// ---------------------------------------------------------------------------
#define LSTR 80

template <int MODE>
__global__ __launch_bounds__(256, 2) void gemm_f16(
    const _Float16* __restrict__ A, const _Float16* __restrict__ B,
    const float* __restrict__ bias1, const float* __restrict__ bias2,
    void* __restrict__ Cout, int M, int N, int K, int nout, int rev) {
  __shared__ _Float16 As[128 * LSTR];
  __shared__ _Float16 Bs[128 * LSTR];

  const int tid = threadIdx.x;
  const int ntn = N >> 7;
  const int tm = blockIdx.x / ntn, tn = blockIdx.x % ntn;
  const int wid = tid >> 6, lane = tid & 63;
  const int wr = wid >> 1, wc = wid & 1;
  const int quad = lane >> 4, l16 = lane & 15;

  const int srow = tid >> 1, seg = tid & 1;
  const int arow = rev ? (M - 1 - (tm * 128 + srow)) : (tm * 128 + srow);
  const int brow = tn * 128 + srow;

  f4 acc[4][4];
#pragma unroll
  for (int i = 0; i < 4; ++i)
#pragma unroll
    for (int j = 0; j < 4; ++j) acc[i][j] = (f4)0.f;

  for (int k0 = 0; k0 < K; k0 += 64) {
    uint4 va[4], vb[4];
    const uint4* gpa = (const uint4*)(A + (size_t)arow * K + k0 + seg * 32);
    const uint4* gpb = (const uint4*)(B + (size_t)brow * K + k0 + seg * 32);
#pragma unroll
    for (int c = 0; c < 4; ++c) va[c] = gpa[c];
#pragma unroll
    for (int c = 0; c < 4; ++c) vb[c] = gpb[c];

    __syncthreads();
    uint4* lpa = (uint4*)&As[srow * LSTR + seg * 32];
    uint4* lpb = (uint4*)&Bs[srow * LSTR + seg * 32];
#pragma unroll
    for (int c = 0; c < 4; ++c) lpa[c] = va[c];
#pragma unroll
    for (int c = 0; c < 4; ++c) lpb[c] = vb[c];
    __syncthreads();

#pragma unroll
    for (int kk = 0; kk < 64; kk += 32) {
      h8 af[4], bf[4];
#pragma unroll
      for (int i = 0; i < 4; ++i) {
        int m = wr * 64 + i * 16 + l16;
        af[i] = *(const h8*)&As[m * LSTR + kk + quad * 8];
        int n = wc * 64 + i * 16 + l16;
        bf[i] = *(const h8*)&Bs[n * LSTR + kk + quad * 8];
      }
#pragma unroll
      for (int i = 0; i < 4; ++i)
#pragma unroll
        for (int j = 0; j < 4; ++j)
          acc[i][j] = __builtin_amdgcn_mfma_f32_16x16x32_f16(af[i], bf[j], acc[i][j], 0, 0, 0);
    }
  }

  const int cm0 = tm * 128 + wr * 64, cn0 = tn * 128 + wc * 64;
#pragma unroll
  for (int i = 0; i < 4; ++i) {
#pragma unroll
    for (int j = 0; j < 4; ++j) {
      int n = cn0 + j * 16 + l16;
#pragma unroll
      for (int r = 0; r < 4; ++r) {
        int m = cm0 + i * 16 + quad * 4 + r;
        float v = acc[i][j][r];
        if (MODE == 0) {
          v += bias1[n] + bias2[n];
          ((_Float16*)Cout)[(size_t)m * N + n] = (_Float16)v;
        } else {
          if (n < nout) ((float*)Cout)[(size_t)m * nout + n] = v + bias1[n];
        }
      }
    }
  }
}

// ---------------------------------------------------------------------------
// Persistent BiLSTM recurrence, R5.
// 128 blocks x 256 thr (4 waves). blk<64 fwd else bwd. Block owns 16 h
// (j0..j0+15) = 64 W_hh rows. Wave wv owns jj {4wv..4wv+3}, lane l:
// gate g=l>>4, kq=l&15. Thread rows: wrow0=g*1024+j0+4wv (+0..3), k-slice
// kq*64..+63 (shared by its 4 rows -> LDS-efficient dot).
// hc: [buf][dir][512] u64; word w = [h2(h[2w],h[2w+1]) | seq32].
// Consumer of step t polls buf t&1 for seq==t (thread polls words 2tid,
// 2tid+1); producer stores seq=t+1 into buf (t+1)&1 (lane0/wave: words
// ib*8+2wv, +1). 2-buffer safety: reaching t+2 data-depends on having
// polled gen t+1, so gen t can't be overwritten early.
// LDS h: double-buffered, 16 segs x 36 dwords (stride-pad: 2-way max).
// ---------------------------------------------------------------------------
__global__ __launch_bounds__(256, 1) void lstm_rec(
    const float* __restrict__ Whh_f, const float* __restrict__ Whh_b,
    const _Float16* __restrict__ xp,   // [2][2048][4096]
    u64* __restrict__ hc,              // [2][2][512]
    _Float16* __restrict__ hhist) {    // [2048][2048]
  const int tid = threadIdx.x;
  const int blk = blockIdx.x;
  const int dir = blk >> 6;
  const int ib = blk & 63;
  const int j0 = ib * 16;
  const int wv = tid >> 6;
  const int l = tid & 63;
  const int g = l >> 4;      // gate 0..3 (i,f,g,o)
  const int kq = l & 15;     // 16 k-slices of 64
  const int q = l & 3;       // cell-replica jj index
  const int wrow0 = g * 1024 + j0 + 4 * wv;

  const float* Whh = dir ? Whh_b : Whh_f;
  const _Float16* xpd = xp + (size_t)dir * (2048u * 4096u);

  __shared__ unsigned int lds_h[2][16 * 36];  // [buf][seg stride 36]
  __shared__ float lds_tr[4 * 16];            // per-wave gate transpose

  // one-time: W_hh[wrow0+j][kq*64 .. +63] -> f16 regs (4 rows x 32 dwords)
  unsigned int w[4][32];
#pragma unroll
  for (int j = 0; j < 4; ++j) {
    const float* wp = Whh + (size_t)(wrow0 + j) * 1024 + kq * 64;
#pragma unroll
    for (int i = 0; i < 16; ++i) {
      float4 v = ((const float4*)wp)[i];
      w[j][2 * i] = packh2(v.x, v.y);
      w[j][2 * i + 1] = packh2(v.z, v.w);
    }
  }

  float c = 0.f;  // cell state for jj=4wv+q (replicated across 16 lanes)

  // x_proj for t=0 (4 consecutive f16 at wrow0)
  uint2 xv = *(const uint2*)(xpd + wrow0);
  h2 x01 = __builtin_bit_cast(h2, xv.x);
  h2 x23 = __builtin_bit_cast(h2, xv.y);
  float xf[4] = {(float)x01[0], (float)x01[1], (float)x23[0], (float)x23[1]};

  for (int t = 0; t < T_LEN; ++t) {
    const int buf = t & 1;
    // ---- poll own 2 words (widx = 2tid, 2tid+1) ----
    unsigned d0, d1;
    {
      u64* src = hc + (((size_t)buf * 2 + dir) * 512 + 2 * tid);
      u64 a = __hip_atomic_load(&src[0], __ATOMIC_RELAXED, __HIP_MEMORY_SCOPE_AGENT);
      u64 b = __hip_atomic_load(&src[1], __ATOMIC_RELAXED, __HIP_MEMORY_SCOPE_AGENT);
      int cnt = 0;
      while ((unsigned)a != (unsigned)t || (unsigned)b != (unsigned)t) {
        if (++cnt > (1 << 12)) break;  // bailout: fail absmax, never hang
        a = __hip_atomic_load(&src[0], __ATOMIC_RELAXED, __HIP_MEMORY_SCOPE_AGENT);
        b = __hip_atomic_load(&src[1], __ATOMIC_RELAXED, __HIP_MEMORY_SCOPE_AGENT);
      }
      d0 = (unsigned)(a >> 32);
      d1 = (unsigned)(b >> 32);
    }

    // prefetch NEXT step's x_proj (after poll loads -> off the vmcnt path)
    int tnx = (t + 1 < T_LEN) ? t + 1 : t;
    uint2 xn = *(const uint2*)(xpd + (size_t)tnx * 4096 + wrow0);

    // stage h payload: dwords 2tid,2tid+1 -> seg tid>>4, offset 2*(tid&15)
    *(uint2*)&lds_h[buf][(tid >> 4) * 36 + 2 * (tid & 15)] = make_uint2(d0, d1);
    __syncthreads();  // single barrier per step

    // ---- dot: 4 rows x 64-elem slice; 8 ds_read_b128, 128 fdot2 ----
    float acc0 = 0.f, acc1 = 0.f, acc2 = 0.f, acc3 = 0.f;
    const uint4* hp = (const uint4*)&lds_h[buf][kq * 36];
#pragma unroll
    for (int i = 0; i < 8; ++i) {
      uint4 hv = hp[i];
      acc0 = fdot2u(w[0][4 * i + 0], hv.x, acc0);
      acc0 = fdot2u(w[0][4 * i + 1], hv.y, acc0);
      acc0 = fdot2u(w[0][4 * i + 2], hv.z, acc0);
      acc0 = fdot2u(w[0][4 * i + 3], hv.w, acc0);
      acc1 = fdot2u(w[1][4 * i + 0], hv.x, acc1);
      acc1 = fdot2u(w[1][4 * i + 1], hv.y, acc1);
      acc1 = fdot2u(w[1][4 * i + 2], hv.z, acc1);
      acc1 = fdot2u(w[1][4 * i + 3], hv.w, acc1);
      acc2 = fdot2u(w[2][4 * i + 0], hv.x, acc2);
      acc2 = fdot2u(w[2][4 * i + 1], hv.y, acc2);
      acc2 = fdot2u(w[2][4 * i + 2], hv.z, acc2);
      acc2 = fdot2u(w[2][4 * i + 3], hv.w, acc2);
      acc3 = fdot2u(w[3][4 * i + 0], hv.x, acc3);
      acc3 = fdot2u(w[3][4 * i + 1], hv.y, acc3);
      acc3 = fdot2u(w[3][4 * i + 2], hv.z, acc3);
      acc3 = fdot2u(w[3][4 * i + 3], hv.w, acc3);
    }
    // butterfly reduce over kq (lane bits 0..3); all lanes get group sums
#pragma unroll
    for (int m = 1; m < 16; m <<= 1) {
      acc0 += __shfl_xor(acc0, m, 64);
      acc1 += __shfl_xor(acc1, m, 64);
      acc2 += __shfl_xor(acc2, m, 64);
      acc3 += __shfl_xor(acc3, m, 64);
    }

    // in-wave transpose: lane (g,kq==0) writes 4 gate-preacts for jj 4wv+0..3
    if (kq == 0) {
      f4 v = {acc0 + xf[0], acc1 + xf[1], acc2 + xf[2], acc3 + xf[3]};
      *(f4*)&lds_tr[wv * 16 + g * 4] = v;
    }
    // same-wave LDS RAW: compiler inserts lgkmcnt wait; no barrier needed
    float pi = lds_tr[wv * 16 + 0 + q];
    float pf = lds_tr[wv * 16 + 4 + q];
    float pg = lds_tr[wv * 16 + 8 + q];
    float po = lds_tr[wv * 16 + 12 + q];

    float ii = sigmoidf_(pi);
    float ff = sigmoidf_(pf);
    float g_ = tanhf_(pg);
    float oo = sigmoidf_(po);
    c = ff * c + ii * g_;
    float h = oo * tanhf_(c);  // h for jj=4wv+q (replicated over 16 lanes)

    // lane0 gathers the wave's 4 h and publishes 2 contiguous u64 words
    float h1 = __shfl(h, 1, 64);
    float h2v = __shfl(h, 2, 64);
    float h3 = __shfl(h, 3, 64);
    if (l == 0) {
      unsigned p01 = packh2(h, h1);
      unsigned p23 = packh2(h2v, h3);
      u64 w0 = ((u64)p01 << 32) | (unsigned)(t + 1);
      u64 w1 = ((u64)p23 << 32) | (unsigned)(t + 1);
      u64* dst = hc + (((size_t)((t + 1) & 1) * 2 + dir) * 512 + (ib * 8 + 2 * wv));
      __hip_atomic_store(&dst[0], w0, __ATOMIC_RELAXED, __HIP_MEMORY_SCOPE_AGENT);
      __hip_atomic_store(&dst[1], w1, __ATOMIC_RELAXED, __HIP_MEMORY_SCOPE_AGENT);
      // hhist AFTER publish: off the critical sync path
      int tout = dir ? (T_LEN - 1 - t) : t;
      *(uint2*)&hhist[(size_t)tout * 2048 + dir * 1024 + j0 + 4 * wv] =
          make_uint2(p01, p23);
    }

    // convert next-step xp (prefetched above)
    x01 = __builtin_bit_cast(h2, xn.x);
    x23 = __builtin_bit_cast(h2, xn.y);
    xf[0] = (float)x01[0]; xf[1] = (float)x01[1];
    xf[2] = (float)x23[0]; xf[3] = (float)x23[1];
  }
}

// ---------------------------------------------------------------------------
extern "C" void kernel_launch(void* const* d_in, const int* in_sizes, int n_in,
                              void* d_out, int out_size, void* d_ws, size_t ws_size,
                              hipStream_t stream) {
  (void)in_sizes; (void)n_in; (void)out_size; (void)ws_size;
  const float* x     = (const float*)d_in[0];
  const float* Wih_f = (const float*)d_in[1];
  const float* Whh_f = (const float*)d_in[2];
  const float* bih_f = (const float*)d_in[3];
  const float* bhh_f = (const float*)d_in[4];
  const float* Wih_b = (const float*)d_in[5];
  const float* Whh_b = (const float*)d_in[6];
  const float* bih_b = (const float*)d_in[7];
  const float* bhh_b = (const float*)d_in[8];
  const float* fcW   = (const float*)d_in[9];
  const float* fcb   = (const float*)d_in[10];

  char* ws = (char*)d_ws;
  _Float16* xf16   = (_Float16*)(ws + 0);
  _Float16* wih16f = (_Float16*)(ws + 4194304);
  _Float16* wih16b = (_Float16*)(ws + 12582912);
  _Float16* fcw16  = (_Float16*)(ws + 20971520);
  _Float16* xp16   = (_Float16*)(ws + 25165824);   // [2][2048][4096]
  _Float16* hhist  = (_Float16*)(ws + 58720256);   // [2048][2048]
  u64*      hc     = (u64*)     (ws + 67108864);   // [2][2][512]

  const size_t SX = 2097152, SW = 4194304, SFC = 2097152;
  const size_t total_cvt = SX + 2 * SW + SFC;

  convert_all<<<dim3((unsigned)((total_cvt + 255) / 256)), 256, 0, stream>>>(
      x, Wih_f, Wih_b, fcW, xf16, wih16f, wih16b, fcw16);
  init_state<<<1, 256, 0, stream>>>(hc);

  gemm_f16<0><<<dim3(512), 256, 0, stream>>>(xf16, wih16f, bih_f, bhh_f,
                                             (void*)xp16, 2048, 4096, 1024, 4096, 0);
  gemm_f16<0><<<dim3(512), 256, 0, stream>>>(xf16, wih16b, bih_b, bhh_b,
                                             (void*)(xp16 + (size_t)2048 * 4096),
                                             2048, 4096, 1024, 4096, 1);

  lstm_rec<<<dim3(128), 256, 0, stream>>>(Whh_f, Whh_b, xp16, hc, hhist);

  gemm_f16<1><<<dim3(128), 256, 0, stream>>>(hhist, fcw16, fcb, nullptr,
                                             d_out, 2048, 1024, 2048, 1000, 0);
}